// Round 4
// baseline (1437.759 us; speedup 1.0000x reference)
//
#include <hip/hip_runtime.h>
#include <hip/hip_bf16.h>
#include <math.h>

// Problem constants: T=2048, B=4096, IN_S=1, H=20, OUT_S=1
#define TT 2048
#define BB 4096
#define HH 20

__device__ __forceinline__ float rcp_fast(float x) {
    return __builtin_amdgcn_rcpf(x);  // v_rcp_f32, ~1 ulp
}
__device__ __forceinline__ float sigm_fast(float x) {
    return rcp_fast(1.0f + __expf(-x));
}
__device__ __forceinline__ float tanh_fast(float x) {
    // tanh(|x|) = (1-e)/(1+e), e = exp(-2|x|) in (0,1]; restore sign.
    float e = __expf(-2.0f * fabsf(x));
    float t = (1.0f - e) * rcp_fast(1.0f + e);
    return copysignf(t, x);
}

// 20-term dot of a weight row against h held as 5 float4 registers.
// Two partial accumulators halve the dependent-FMA depth.
__device__ __forceinline__ float dot20(const float* __restrict__ w,
                                       const float4 q[5], float init) {
    float s0 = init, s1 = 0.0f;
    s0 = fmaf(w[0],  q[0].x, s0);  s1 = fmaf(w[1],  q[0].y, s1);
    s0 = fmaf(w[2],  q[0].z, s0);  s1 = fmaf(w[3],  q[0].w, s1);
    s0 = fmaf(w[4],  q[1].x, s0);  s1 = fmaf(w[5],  q[1].y, s1);
    s0 = fmaf(w[6],  q[1].z, s0);  s1 = fmaf(w[7],  q[1].w, s1);
    s0 = fmaf(w[8],  q[2].x, s0);  s1 = fmaf(w[9],  q[2].y, s1);
    s0 = fmaf(w[10], q[2].z, s0);  s1 = fmaf(w[11], q[2].w, s1);
    s0 = fmaf(w[12], q[3].x, s0);  s1 = fmaf(w[13], q[3].y, s1);
    s0 = fmaf(w[14], q[3].z, s0);  s1 = fmaf(w[15], q[3].w, s1);
    s0 = fmaf(w[16], q[4].x, s0);  s1 = fmaf(w[17], q[4].y, s1);
    s0 = fmaf(w[18], q[4].z, s0);  s1 = fmaf(w[19], q[4].w, s1);
    return s0 + s1;
}

// One wave per block; each lane runs TWO independent batch chains (A,B) for
// its hidden unit j. Lanes [0..19],[20..39],[40..59] = 3 batch-groups; chain A
// = batches blk*6+group, chain B = blk*6+3+group. Weights (w_hh/w_out/w_ih)
// are SHARED between chains (same j) — ILP doubles, register cost grows only
// by the per-chain state. Lanes 60..63 idle (own LDS region, never store).
__global__ __launch_bounds__(64, 1) void lstm_fused_kernel(
    const float* __restrict__ u,      // [T, B, 1]
    const float* __restrict__ W_ih,   // [4H, 1]
    const float* __restrict__ W_hh,   // [4H, H]
    const float* __restrict__ W_out,  // [1, H]
    float* __restrict__ y)            // [T, B, 1]
{
    // Single buffer per chain: same-wave DS ops execute in order, so the next
    // step's write cannot pass this step's reads — no WAR hazard, no parity.
    __shared__ __align__(16) float hbufA[4][HH];
    __shared__ __align__(16) float hbufB[4][HH];

    const int lane  = threadIdx.x;
    const int group = lane / HH;          // 0..3 (3 == idle)
    const int j     = lane - group * HH;  // 0..19
    const int bA = blockIdx.x * 6 + group;
    const int bB = blockIdx.x * 6 + 3 + group;
    const bool actA = (group < 3) && (bA < BB);
    const bool actB = (group < 3) && (bB < BB);
    const int lbA = actA ? bA : 0;
    const int lbB = actB ? bB : 0;

    // ---- Weights in registers (shared by both chains) ----
    float w_hh[4][HH];
    float w_ih[4];
    #pragma unroll
    for (int g = 0; g < 4; ++g) {
        w_ih[g] = W_ih[g * HH + j];
        #pragma unroll
        for (int k = 0; k < HH; ++k)
            w_hh[g][k] = W_hh[(g * HH + j) * HH + k];
    }
    float w_out[HH];
    #pragma unroll
    for (int k = 0; k < HH; ++k) w_out[k] = W_out[k];

    // ---- Recurrent state: h as 5 float4 regs per chain (fed by ds_read_b128) ----
    float4 qA[5], qB[5];
    #pragma unroll
    for (int m = 0; m < 5; ++m) {
        qA[m] = make_float4(0.f, 0.f, 0.f, 0.f);
        qB[m] = make_float4(0.f, 0.f, 0.f, 0.f);
    }
    float cA = 0.0f, cB = 0.0f;

    const float* __restrict__ upA = u + lbA;
    const float* __restrict__ upB = u + lbB;
    float* __restrict__ ypA = y + lbA;
    float* __restrict__ ypB = y + lbB;

    float uA[4], uB[4];
    #pragma unroll
    for (int k = 0; k < 4; ++k) {
        uA[k] = upA[(size_t)k * BB];
        uB[k] = upB[(size_t)k * BB];
    }

    for (int t4 = 0; t4 < TT; t4 += 4) {
        const int tn = (t4 + 4 < TT) ? (t4 + 4) : t4;
        float uAn[4], uBn[4];
        #pragma unroll
        for (int k = 0; k < 4; ++k) {
            uAn[k] = upA[(size_t)(tn + k) * BB];
            uBn[k] = upB[(size_t)(tn + k) * BB];
        }

        float yA4[4], yB4[4];

        #pragma unroll
        for (int tt = 0; tt < 4; ++tt) {
            // --- chain A gates ---
            const float uvA = uA[tt];
            float gA0 = dot20(w_hh[0], qA, uvA * w_ih[0]);
            float gA1 = dot20(w_hh[1], qA, uvA * w_ih[1]);
            float gA2 = dot20(w_hh[2], qA, uvA * w_ih[2]);
            float gA3 = dot20(w_hh[3], qA, uvA * w_ih[3]);
            // --- chain B gates (independent — interleaves with A's latencies) ---
            const float uvB = uB[tt];
            float gB0 = dot20(w_hh[0], qB, uvB * w_ih[0]);
            float gB1 = dot20(w_hh[1], qB, uvB * w_ih[1]);
            float gB2 = dot20(w_hh[2], qB, uvB * w_ih[2]);
            float gB3 = dot20(w_hh[3], qB, uvB * w_ih[3]);

            const float iA = sigm_fast(gA0), fA = sigm_fast(gA1);
            const float gA = tanh_fast(gA2), oA = sigm_fast(gA3);
            cA = fmaf(fA, cA, iA * gA);
            const float hA = oA * tanh_fast(cA);

            const float iB = sigm_fast(gB0), fB = sigm_fast(gB1);
            const float gB = tanh_fast(gB2), oB = sigm_fast(gB3);
            cB = fmaf(fB, cB, iB * gB);
            const float hB = oB * tanh_fast(cB);

            // Broadcast both h's; one drain; read both back as float4s.
            hbufA[group][j] = hA;
            hbufB[group][j] = hB;
            asm volatile("s_waitcnt lgkmcnt(0)" ::: "memory");
            const float4* __restrict__ sA = (const float4*)(&hbufA[group][0]);
            const float4* __restrict__ sB = (const float4*)(&hbufB[group][0]);
            #pragma unroll
            for (int m = 0; m < 5; ++m) { qA[m] = sA[m]; qB[m] = sB[m]; }

            // y_t = W_out . h_t (redundant across lanes; j==0 stores)
            yA4[tt] = dot20(w_out, qA, 0.0f);
            yB4[tt] = dot20(w_out, qB, 0.0f);
        }

        if (j == 0) {
            #pragma unroll
            for (int k = 0; k < 4; ++k) {
                if (actA) ypA[(size_t)(t4 + k) * BB] = yA4[k];
                if (actB) ypB[(size_t)(t4 + k) * BB] = yB4[k];
            }
        }

        #pragma unroll
        for (int k = 0; k < 4; ++k) { uA[k] = uAn[k]; uB[k] = uBn[k]; }
    }
}

extern "C" void kernel_launch(void* const* d_in, const int* in_sizes, int n_in,
                              void* d_out, int out_size, void* d_ws, size_t ws_size,
                              hipStream_t stream) {
    const float* u     = (const float*)d_in[0];   // [2048, 4096, 1]
    const float* W_ih  = (const float*)d_in[1];   // [80, 1]
    const float* W_hh  = (const float*)d_in[2];   // [80, 20]
    const float* W_out = (const float*)d_in[3];   // [1, 20]
    float* y = (float*)d_out;                      // [2048, 4096, 1]

    const int blocks = (BB + 5) / 6;  // 6 batches per single-wave block -> 683
    lstm_fused_kernel<<<dim3(blocks), dim3(64), 0, stream>>>(u, W_ih, W_hh, W_out, y);
}

// Round 5
// 980.427 us; speedup vs baseline: 1.4665x; 1.4665x over previous
//
#include <hip/hip_runtime.h>
#include <hip/hip_bf16.h>
#include <math.h>

// Problem constants: T=2048, B=4096, IN_S=1, H=20, OUT_S=1
#define TT 2048
#define BB 4096
#define HH 20

typedef float v2f __attribute__((ext_vector_type(2)));

#define L2E 1.4426950408889634f  // log2(e)

__device__ __forceinline__ float rcp_fast(float x)  { return __builtin_amdgcn_rcpf(x); }
__device__ __forceinline__ float exp2_fast(float x) { return __builtin_amdgcn_exp2f(x); }

// Packed dual fp32 FMA (VOP3P). op_sel/op_sel_hi select which dword of each
// 64-bit source feeds the low/high lane of the packed op. We use them to
// BROADCAST one half of the h pair into both halves — so h can stay in the
// natural (h_2m, h_2m+1) register pairs read straight from LDS (R3's mistake
// was materializing a duplicated-h LDS layout instead).
__device__ __forceinline__ void pk_fma_b0(v2f& acc, v2f w, v2f h) {
    // both halves read h.low
    asm("v_pk_fma_f32 %0, %1, %2, %0 op_sel:[0,0,0] op_sel_hi:[1,0,1]"
        : "+v"(acc) : "v"(w), "v"(h));
}
__device__ __forceinline__ void pk_fma_b1(v2f& acc, v2f w, v2f h) {
    // both halves read h.high
    asm("v_pk_fma_f32 %0, %1, %2, %0 op_sel:[0,1,0] op_sel_hi:[1,1,1]"
        : "+v"(acc) : "v"(w), "v"(h));
}
__device__ __forceinline__ void pk_fma(v2f& acc, v2f w, v2f h) {
    // normal packed: lo*lo, hi*hi
    asm("v_pk_fma_f32 %0, %1, %2, %0 op_sel:[0,0,0] op_sel_hi:[1,1,1]"
        : "+v"(acc) : "v"(w), "v"(h));
}

// One wave per block. Lanes [0..19],[20..39],[40..59] = 3 batches; lane ->
// (group, unit j). Lanes 60..63 idle (own LDS region, never store).
__global__ __launch_bounds__(64, 1) void lstm_fused_kernel(
    const float* __restrict__ u,      // [T, B, 1]
    const float* __restrict__ W_ih,   // [4H, 1]
    const float* __restrict__ W_hh,   // [4H, H]
    const float* __restrict__ W_out,  // [1, H]
    float* __restrict__ y)            // [T, B, 1]
{
    // Single buffer: same-wave DS ops are in-order, so next step's write can't
    // pass this step's reads (WAR-safe, verified R4). lgkmcnt drain gives
    // cross-lane visibility without s_barrier / vmcnt drain.
    __shared__ __align__(16) float hbuf[4][HH];

    const int lane  = threadIdx.x;
    const int group = lane / HH;          // 0..3 (3 == idle)
    const int j     = lane - group * HH;  // 0..19
    const int b_real = blockIdx.x * 3 + group;
    const bool active = (group < 3) && (b_real < BB);
    const int b = active ? b_real : 0;

    // h_{-1} = 0 for all groups (incl. idle region, keeps garbage finite).
    for (int i = lane; i < 4 * HH; i += 64) ((float*)hbuf)[i] = 0.0f;
    asm volatile("s_waitcnt lgkmcnt(0)" ::: "memory");

    // ---- Weights in registers, packed by gate pair, PRESCALED so that the
    // gate pre-activations are already in exp2 domain:
    //   i,f,o rows * (-log2 e)  ->  sigmoid(x) = rcp(1 + exp2(a))
    //   g row     * (2 log2 e)  ->  tanh(x) from e = exp2(-|a|), sign(a)=sign(x)
    v2f w01[HH];  // (i-row, f-row), scaled -L2E
    v2f w23[HH];  // (g-row * 2L2E, o-row * -L2E)
    #pragma unroll
    for (int k = 0; k < HH; ++k) {
        w01[k].x = -L2E       * W_hh[(0 * HH + j) * HH + k];
        w01[k].y = -L2E       * W_hh[(1 * HH + j) * HH + k];
        w23[k].x = (2.0f*L2E) * W_hh[(2 * HH + j) * HH + k];
        w23[k].y = -L2E       * W_hh[(3 * HH + j) * HH + k];
    }
    v2f wih01, wih23;
    wih01.x = -L2E       * W_ih[0 * HH + j];
    wih01.y = -L2E       * W_ih[1 * HH + j];
    wih23.x = (2.0f*L2E) * W_ih[2 * HH + j];
    wih23.y = -L2E       * W_ih[3 * HH + j];
    v2f wo2[HH / 2];  // (W_out[2m], W_out[2m+1]) — unscaled
    #pragma unroll
    for (int m = 0; m < HH / 2; ++m) { wo2[m].x = W_out[2 * m]; wo2[m].y = W_out[2 * m + 1]; }

    float c = 0.0f;
    const float* __restrict__ up = u + b;
    float* __restrict__ yp = y + b;

    float u_cur[4];
    #pragma unroll
    for (int k = 0; k < 4; ++k) u_cur[k] = up[(size_t)k * BB];

    const v2f* __restrict__ hs = (const v2f*)(&hbuf[group][0]);

    for (int t4 = 0; t4 < TT; t4 += 4) {
        const int tn = (t4 + 4 < TT) ? (t4 + 4) : t4;
        float u_nxt[4];
        #pragma unroll
        for (int k = 0; k < 4; ++k) u_nxt[k] = up[(size_t)(tn + k) * BB];

        float y4[4];  // y4[tt] = y_{t4+tt-1} (y reads the h broadcast one step late)

        #pragma unroll
        for (int tt = 0; tt < 4; ++tt) {
            // ---- read h_{t-1} as 10 even-aligned pairs (ds_read_b64/b128) ----
            v2f h2[10];
            #pragma unroll
            for (int m = 0; m < 10; ++m) h2[m] = hs[m];

            const float uv = u_cur[tt];
            v2f a01; a01.x = uv * wih01.x; a01.y = uv * wih01.y;
            v2f a23; a23.x = uv * wih23.x; a23.y = uv * wih23.y;
            v2f ay = {0.0f, 0.0f};

            // 40 pk_fma (gates) + 10 pk_fma (y), round-robin so each acc's
            // dep distance is >= 3 insts (6 cyc > 4-cyc FMA latency).
            #pragma unroll
            for (int m = 0; m < 10; ++m) {
                v2f hp = h2[m];
                pk_fma_b0(a01, w01[2 * m],     hp);
                pk_fma_b0(a23, w23[2 * m],     hp);
                pk_fma   (ay,  wo2[m],         hp);
                pk_fma_b1(a01, w01[2 * m + 1], hp);
                pk_fma_b1(a23, w23[2 * m + 1], hp);
            }
            y4[tt] = ay.x + ay.y;  // = y_{t-1}

            // ---- activations (exp2 domain; v_exp/v_rcp quarter-rate) ----
            const float ig = rcp_fast(1.0f + exp2_fast(a01.x));
            const float fg = rcp_fast(1.0f + exp2_fast(a01.y));
            const float og = rcp_fast(1.0f + exp2_fast(a23.y));
            const float ag = a23.x;                      // 2*log2e*x_g
            const float eg = exp2_fast(-fabsf(ag));      // e^{-2|x_g|}
            const float tg = (1.0f - eg) * rcp_fast(1.0f + eg);
            const float gg = copysignf(tg, ag);

            c = fmaf(fg, c, ig * gg);
            const float ec = exp2_fast(-2.0f * L2E * fabsf(c));
            const float tc = (1.0f - ec) * rcp_fast(1.0f + ec);
            const float h  = og * copysignf(tc, c);

            // ---- broadcast h_t ----
            hbuf[group][j] = h;
            asm volatile("s_waitcnt lgkmcnt(0)" ::: "memory");
        }

        if (active && j == 0) {
            #pragma unroll
            for (int k = 0; k < 4; ++k) {
                const int idx = t4 - 1 + k;
                if (idx >= 0) yp[(size_t)idx * BB] = y4[k];
            }
        }

        #pragma unroll
        for (int k = 0; k < 4; ++k) u_cur[k] = u_nxt[k];
    }

    // Epilogue: y_{T-1} from the final h broadcast.
    {
        v2f ay = {0.0f, 0.0f};
        #pragma unroll
        for (int m = 0; m < 10; ++m) pk_fma(ay, wo2[m], hs[m]);
        if (active && j == 0) yp[(size_t)(TT - 1) * BB] = ay.x + ay.y;
    }
}

extern "C" void kernel_launch(void* const* d_in, const int* in_sizes, int n_in,
                              void* d_out, int out_size, void* d_ws, size_t ws_size,
                              hipStream_t stream) {
    const float* u     = (const float*)d_in[0];   // [2048, 4096, 1]
    const float* W_ih  = (const float*)d_in[1];   // [80, 1]
    const float* W_hh  = (const float*)d_in[2];   // [80, 20]
    const float* W_out = (const float*)d_in[3];   // [1, 20]
    float* y = (float*)d_out;                      // [2048, 4096, 1]

    const int blocks = (BB + 2) / 3;  // 3 batches per single-wave block -> 1366
    lstm_fused_kernel<<<dim3(blocks), dim3(64), 0, stream>>>(u, W_ih, W_hh, W_out, y);
}